// Round 1
// baseline (310.693 us; speedup 1.0000x reference)
//
#include <hip/hip_runtime.h>
#include <hip/hip_bf16.h>
#include <stdint.h>

#define N_NODES  50000
#define N_EDGES  800000
#define N_GRAPHS 512

#define BINSZ   128
#define NBIN    ((N_NODES + BINSZ - 1)/BINSZ)    // 391
#define NCHUNK  256
#define CHUNK   ((N_EDGES + NCHUNK - 1)/NCHUNK)  // 3125
#define MAXBIN  3072
#define NB64    ((N_NODES + 63)/64)              // 782

typedef __attribute__((ext_vector_type(8))) short  short8;
typedef __attribute__((ext_vector_type(4))) float  floatx4;
typedef unsigned short u16;
typedef unsigned int   u32;

__device__ __forceinline__ u16 f2b(float f){
  u32 u = __float_as_uint(f);
  u = (u + 0x7FFFu + ((u >> 16) & 1u)) >> 16;   // RNE
  return (u16)u;
}
__device__ __forceinline__ u32 pack2(float a, float b){
  return (u32)f2b(a) | ((u32)f2b(b) << 16);
}
__device__ __forceinline__ float blo(u32 v){ return __uint_as_float(v << 16); }
__device__ __forceinline__ float bhi(u32 v){ return __uint_as_float(v & 0xFFFF0000u); }
__device__ __forceinline__ float b2f(u16 s){ return __uint_as_float(((u32)s) << 16); }

// gather-accumulate one node's neighbor rows (bf16 X, 128ch).
// half-waves (sub 0/1) process alternate edges; lane ln holds ch[4ln..4ln+3].
// Returns merged sums in all lanes (sub0 == sub1 after merge).
__device__ __forceinline__ floatx4 gather_node(const uint2* __restrict__ Xu,
    const int* __restrict__ col, u32 r, int lane, int sub, int ln, int* degOut){
  int cs = (int)(r >> 11), d = (int)(r & 2047), ce = cs + d;
  float a0 = 0.f, a1 = 0.f, a2 = 0.f, a3 = 0.f;
  for (int cb = cs; cb < ce; cb += 64){
    int cnt = min(64, ce - cb);
    int idx = 0;
    if (cb + lane < ce) idx = col[cb + lane];
    int k = 0;
    // 8-edge unroll: 4 independent row-gathers in flight per half-wave
    for (; k + 8 <= cnt; k += 8){
      int jA = __shfl(idx, k + sub);
      int jB = __shfl(idx, k + 2 + sub);
      int jC = __shfl(idx, k + 4 + sub);
      int jD = __shfl(idx, k + 6 + sub);
      uint2 vA = Xu[jA*32 + ln];
      uint2 vB = Xu[jB*32 + ln];
      uint2 vC = Xu[jC*32 + ln];
      uint2 vD = Xu[jD*32 + ln];
      a0 += (blo(vA.x) + blo(vB.x)) + (blo(vC.x) + blo(vD.x));
      a1 += (bhi(vA.x) + bhi(vB.x)) + (bhi(vC.x) + bhi(vD.x));
      a2 += (blo(vA.y) + blo(vB.y)) + (blo(vC.y) + blo(vD.y));
      a3 += (bhi(vA.y) + bhi(vB.y)) + (bhi(vC.y) + bhi(vD.y));
    }
    for (; k + 2 <= cnt; k += 2){
      int j = __shfl(idx, k + sub);
      uint2 v = Xu[j*32 + ln];
      a0 += blo(v.x); a1 += bhi(v.x); a2 += blo(v.y); a3 += bhi(v.y);
    }
    if (k < cnt){
      int j = __shfl(idx, k);
      if (sub == 0){
        uint2 v = Xu[j*32 + ln];
        a0 += blo(v.x); a1 += bhi(v.x); a2 += blo(v.y); a3 += bhi(v.y);
      }
    }
  }
  a0 += __shfl_xor(a0, 32); a1 += __shfl_xor(a1, 32);
  a2 += __shfl_xor(a2, 32); a3 += __shfl_xor(a3, 32);
  *degOut = d;
  floatx4 out = {a0, a1, a2, a3};
  return out;
}

// ---- fused prep (cast X, weight prep, graph bounds) + edge scatter ----------
#define PREP_CAST   6250
#define PREP_W2     (PREP_CAST + 256)
#define PREP_MLP    (PREP_W2 + 128)
#define PREP_BND    (PREP_MLP + 3)
#define PREP_TOT    (PREP_BND + NCHUNK)
__launch_bounds__(256)
__global__ void k_prepsc(const float4* __restrict__ x, uint2* __restrict__ X1,
                         const float* __restrict__ Wrel1, const float* __restrict__ Wroot1,
                         const float* __restrict__ Wrel2, const float* __restrict__ Wroot2,
                         u16* __restrict__ wcat,
                         const float* __restrict__ W1, const float* __restrict__ W2,
                         u16* __restrict__ wm,
                         const int* __restrict__ batch, int* __restrict__ start,
                         const int* __restrict__ src, const int* __restrict__ dst,
                         int* __restrict__ bincur, u32* __restrict__ rec){
  __shared__ int h[NBIN];
  __shared__ int cur[NBIN];
  int blk = blockIdx.x, t = threadIdx.x;
  if (blk < PREP_CAST){
    int i = blk*256 + t;                       // exactly 1,600,000
    float4 v = x[i];
    X1[i] = make_uint2(pack2(v.x, v.y), pack2(v.z, v.w));
  } else if (blk < PREP_W2){
    int id = (blk - PREP_CAST)*256 + t;        // 65536
    int l = id >> 15;
    int r = id & 32767;
    int n = r >> 8;
    int k = r & 255;
    const float* Wrel  = l ? Wrel2  : Wrel1;
    const float* Wroot = l ? Wroot2 : Wroot1;
    float w = (k < 128) ? Wrel[k*128 + n] : Wroot[(k-128)*128 + n];
    int c = k >> 3, j = k & 7;
    wcat[l*32768 + n*256 + ((c ^ (n & 15)) << 3) + j] = f2b(w);
  } else if (blk < PREP_MLP){
    int id = (blk - PREP_W2)*256 + t;          // 32768
    int l = id >> 14;
    int r = id & 16383;
    int n = r >> 7;
    int k = r & 127;
    const float* W = l ? W2 : W1;
    wm[l*16384 + n*128 + k] = f2b(W[k*128 + n]);
  } else if (blk < PREP_BND){
    int g = (blk - PREP_MLP)*256 + t;
    if (g <= N_GRAPHS){
      int lo = 0, hi = N_NODES;
      while (lo < hi){ int mid = (lo + hi) >> 1; if (batch[mid] < g) lo = mid + 1; else hi = mid; }
      start[g] = lo;
    }
  } else {
    // scatter: fused hist + range-reserve (bincur is bin-LOCAL, zeroed by memset)
    int cblk = blk - PREP_BND;
    for (int i = t; i < NBIN; i += 256) h[i] = 0;
    __syncthreads();
    int base = cblk*CHUNK;
    int end  = min(base + CHUNK, N_EDGES);
    for (int i = base + t; i < end; i += 256) atomicAdd(&h[dst[i] >> 7], 1);
    __syncthreads();
    for (int i = t; i < NBIN; i += 256){
      int c = h[i];
      cur[i] = i*MAXBIN + (c ? atomicAdd(&bincur[i], c) : 0);
    }
    __syncthreads();
    for (int i = base + t; i < end; i += 256){
      int d = dst[i], sv = src[i];
      int b = d >> 7;
      int p = atomicAdd(&cur[b], 1);
      rec[p] = (u32)(((d & 127) << 16) | sv);
    }
  }
}

// ---- CSR step 2: per-bin node-ordered segment; rp[node] = (start<<11)|deg ---
__global__ void k_bincsr(const u32* __restrict__ rec, const int* __restrict__ bincur,
                         u32* __restrict__ rp, int* __restrict__ col){
  __shared__ u32 recs[MAXBIN];
  __shared__ int colL[MAXBIN];
  __shared__ int deg[BINSZ];
  __shared__ int cursor[BINSZ];
  __shared__ int sc[BINSZ];
  int b = blockIdx.x, t = threadIdx.x;
  int s0 = b*MAXBIN;
  int n = bincur[b];                 // bin-local count
  if (t < BINSZ) deg[t] = 0;
  for (int i = t; i < n; i += 256) recs[i] = rec[s0 + i];
  __syncthreads();
  for (int i = t; i < n; i += 256) atomicAdd(&deg[(recs[i] >> 16) & 127], 1);
  __syncthreads();
  if (t < BINSZ) sc[t] = deg[t];
  __syncthreads();
  for (int off = 1; off < BINSZ; off <<= 1){
    int u = 0;
    if (t < BINSZ && t >= off) u = sc[t - off];
    __syncthreads();
    if (t < BINSZ) sc[t] += u;
    __syncthreads();
  }
  if (t < BINSZ){
    int d = deg[t];
    int pref = sc[t] - d;
    cursor[t] = pref;
    int node = b*BINSZ + t;
    if (node < N_NODES) rp[node] = (u32)((s0 + pref) << 11) | (u32)min(d, 2047);
  }
  __syncthreads();
  for (int i = t; i < n; i += 256){
    u32 r = recs[i];
    int p = atomicAdd(&cursor[(r >> 16) & 127], 1);
    colL[p] = (int)(r & 0xFFFFu);
  }
  __syncthreads();
  for (int i = t; i < n; i += 256) col[s0 + i] = colL[i];
}

// ---- fused layer: per-block aggregate 64 nodes -> LDS M-tile -> GEMM -------
// Xout = relu([M|X] @ Wcat + brel), M computed in-block (no global M).
// LDS M-tile is XOR-swizzled ((chunk16 ^ (row&15))<<4) for conflict-free b128.
__launch_bounds__(256, 4)
__global__ void k_layer(const u16* __restrict__ X, const u32* __restrict__ rp,
                        const int* __restrict__ col, const u16* __restrict__ Wcat,
                        const float* __restrict__ brel, u16* __restrict__ Xout){
  __shared__ u16 Mt[64*128];                    // 16 KB, swizzled
  int t = threadIdx.x, wave = t >> 6, lane = t & 63;
  int sub = lane >> 5, ln = lane & 31;
  int base = blockIdx.x*64;
  const uint2* Xu = (const uint2*)X;

  // Phase A: gather-aggregate; wave w owns local rows w, w+4, ...
  for (int lr = wave; lr < 64; lr += 4){
    int node = base + lr;
    if (node < N_NODES){
      int d;
      floatx4 a = gather_node(Xu, col, rp[node], lane, sub, ln, &d);
      if (sub == 0){
        float di = 1.0f / (float)max(d, 1);
        *(uint2*)((char*)Mt + lr*256 + ((((ln>>1) ^ (lr & 15)) << 4) + (ln & 1)*8))
            = make_uint2(pack2(a[0]*di, a[1]*di), pack2(a[2]*di, a[3]*di));
      }
    }
  }
  __syncthreads();

  // Phase B: GEMM. A: k<128 from LDS M-tile, k>=128 from global X. B via L1/L2.
  int l15 = lane & 15, quad = lane >> 4;
  int wy = wave >> 1, wx = wave & 1;
  floatx4 acc[2][4] = {};
  #pragma unroll
  for (int k0 = 0; k0 < 256; k0 += 32){
    short8 a[2];
    if (k0 < 128){
      #pragma unroll
      for (int mt = 0; mt < 2; mt++){
        int r = wy*32 + mt*16 + l15;
        int c = (k0 >> 3) + quad;               // 0..15
        a[mt] = *(const short8*)((const char*)Mt + r*256 + ((c ^ (r & 15)) << 4));
      }
    } else {
      #pragma unroll
      for (int mt = 0; mt < 2; mt++){
        int row = base + wy*32 + mt*16 + l15;
        if (row > N_NODES-1) row = N_NODES-1;   // clamp; stores masked
        a[mt] = *(const short8*)(X + row*128 + (k0 - 128) + quad*8);
      }
    }
    #pragma unroll
    for (int nt = 0; nt < 4; nt++){
      int n = wx*64 + nt*16 + l15;
      int c = (k0 >> 3) + quad;                 // 0..31
      short8 b = *(const short8*)(Wcat + n*256 + ((c ^ (n & 15)) << 3));
      #pragma unroll
      for (int mt = 0; mt < 2; mt++)
        acc[mt][nt] = __builtin_amdgcn_mfma_f32_16x16x32_bf16(a[mt], b, acc[mt][nt], 0, 0, 0);
    }
  }

  float bc[4];
  #pragma unroll
  for (int nt = 0; nt < 4; nt++) bc[nt] = brel[wx*64 + nt*16 + l15];

  #pragma unroll
  for (int mt = 0; mt < 2; mt++){
    int rbase = base + wy*32 + mt*16 + quad*4;
    #pragma unroll
    for (int r = 0; r < 4; r++){
      int row = rbase + r;
      if (row < N_NODES){
        #pragma unroll
        for (int nt = 0; nt < 4; nt++){
          int n = wx*64 + nt*16 + l15;
          Xout[row*128 + n] = f2b(fmaxf(acc[mt][nt][r] + bc[nt], 0.f));
        }
      }
    }
  }
}

// ---- fused agg3 + pool + conv3: Gb[g] = pool(agg(X3))@Wrel3 + pool(X3)@Wroot3 + brel3
// pooled-mean of per-node means is linear: no per-node M3 is materialized.
__launch_bounds__(512)
__global__ void k_aggpool(const u16* __restrict__ X3, const u32* __restrict__ rp,
                          const int* __restrict__ col, const int* __restrict__ start,
                          const float* __restrict__ Wrel, const float* __restrict__ Wroot,
                          const float* __restrict__ brel, u16* __restrict__ Gb){
  __shared__ float smM[8][128];
  __shared__ float smX[8][128];
  __shared__ float pmS[128], pxS[128], part[256];
  int g = blockIdx.x;
  int t = threadIdx.x, wave = t >> 6, lane = t & 63;
  int sub = lane >> 5, ln = lane & 31;
  int s = start[g], e = start[g+1];
  const uint2* Xu = (const uint2*)X3;

  float gm0=0.f, gm1=0.f, gm2=0.f, gm3=0.f;
  for (int i = s + wave; i < e; i += 8){
    int d;
    floatx4 a = gather_node(Xu, col, rp[i], lane, sub, ln, &d);
    float di = 1.0f / (float)max(d, 1);
    gm0 += a[0]*di; gm1 += a[1]*di; gm2 += a[2]*di; gm3 += a[3]*di;
  }
  float gx0=0.f, gx1=0.f, gx2=0.f, gx3=0.f;
  for (int i = s + wave*2 + sub; i < e; i += 16){
    uint2 v = Xu[i*32 + ln];
    gx0 += blo(v.x); gx1 += bhi(v.x); gx2 += blo(v.y); gx3 += bhi(v.y);
  }
  gx0 += __shfl_xor(gx0, 32); gx1 += __shfl_xor(gx1, 32);
  gx2 += __shfl_xor(gx2, 32); gx3 += __shfl_xor(gx3, 32);
  if (sub == 0){
    smM[wave][4*ln+0] = gm0; smM[wave][4*ln+1] = gm1;
    smM[wave][4*ln+2] = gm2; smM[wave][4*ln+3] = gm3;
    smX[wave][4*ln+0] = gx0; smX[wave][4*ln+1] = gx1;
    smX[wave][4*ln+2] = gx2; smX[wave][4*ln+3] = gx3;
  }
  __syncthreads();
  if (t < 128){
    float inv = 1.0f / (float)max(e - s, 1);
    float m = 0.f, xx = 0.f;
    #pragma unroll
    for (int w = 0; w < 8; w++){ m += smM[w][t]; xx += smX[w][t]; }
    pmS[t] = m*inv; pxS[t] = xx*inv;
  }
  __syncthreads();
  if (t < 256){
    int n = t & 127, half = t >> 7;
    const float* W = half ? Wroot : Wrel;
    const float* S = half ? pxS : pmS;
    float a = 0.f;
    for (int k = 0; k < 128; k++) a = fmaf(S[k], W[k*128 + n], a);
    part[t] = a;
  }
  __syncthreads();
  if (t < 128) Gb[g*128 + t] = f2b(part[t] + part[t + 128] + brel[t]);
}

// ---- fused MLP (8 blocks x 64 rows) ----------------------------------------
#define APAD 136
__launch_bounds__(256)
__global__ void k_mlp(const u16* __restrict__ Gb, const u16* __restrict__ wm,
                      const float* __restrict__ b1, const float* __restrict__ b2,
                      const float* __restrict__ Wo, const float* __restrict__ bo,
                      float* __restrict__ out){
  __shared__ u16 Apad[64*APAD];
  int t = threadIdx.x;
  int wave = t >> 6, lane = t & 63;
  int l15 = lane & 15, quad = lane >> 4;
  int R = blockIdx.x*64;

  floatx4 acc[8] = {};
  #pragma unroll
  for (int k0 = 0; k0 < 128; k0 += 32){
    int row = R + wave*16 + l15;
    short8 a = *(const short8*)(Gb + row*128 + k0 + quad*8);
    #pragma unroll
    for (int nt = 0; nt < 8; nt++){
      short8 b = *(const short8*)(wm + (nt*16 + l15)*128 + k0 + quad*8);
      acc[nt] = __builtin_amdgcn_mfma_f32_16x16x32_bf16(a, b, acc[nt], 0, 0, 0);
    }
  }
  #pragma unroll
  for (int nt = 0; nt < 8; nt++){
    int coln = nt*16 + l15;
    float bc = b1[coln];
    int lmb = wave*16 + quad*4;
    #pragma unroll
    for (int r = 0; r < 4; r++)
      Apad[(lmb + r)*APAD + coln] = f2b(fmaxf(acc[nt][r] + bc, 0.f));
  }
  __syncthreads();

  floatx4 acc2[8] = {};
  #pragma unroll
  for (int k0 = 0; k0 < 128; k0 += 32){
    short8 a = *(const short8*)(Apad + (wave*16 + l15)*APAD + k0 + quad*8);
    #pragma unroll
    for (int nt = 0; nt < 8; nt++){
      short8 b = *(const short8*)(wm + 16384 + (nt*16 + l15)*128 + k0 + quad*8);
      acc2[nt] = __builtin_amdgcn_mfma_f32_16x16x32_bf16(a, b, acc2[nt], 0, 0, 0);
    }
  }
  __syncthreads();
  #pragma unroll
  for (int nt = 0; nt < 8; nt++){
    int coln = nt*16 + l15;
    float bc = b2[coln];
    int lmb = wave*16 + quad*4;
    #pragma unroll
    for (int r = 0; r < 4; r++)
      Apad[(lmb + r)*APAD + coln] = f2b(fmaxf(acc2[nt][r] + bc, 0.f));
  }
  __syncthreads();

  if (t < 128){
    int row = t >> 1;
    int c0  = (t & 1)*4;
    float o0 = bo[c0], o1 = bo[c0+1], o2 = bo[c0+2], o3 = bo[c0+3];
    for (int k = 0; k < 128; k++){
      float h = b2f(Apad[row*APAD + k]);
      const float* w = Wo + k*8 + c0;
      o0 = fmaf(h, w[0], o0); o1 = fmaf(h, w[1], o1);
      o2 = fmaf(h, w[2], o2); o3 = fmaf(h, w[3], o3);
    }
    float* op = out + (R + row)*8 + c0;
    op[0] = o0; op[1] = o1; op[2] = o2; op[3] = o3;
  }
}

extern "C" void kernel_launch(void* const* d_in, const int* in_sizes, int n_in,
                              void* d_out, int out_size, void* d_ws, size_t ws_size,
                              hipStream_t stream){
  const float* x     = (const float*)d_in[0];
  const int*   ei    = (const int*)d_in[1];
  const int*   batch = (const int*)d_in[2];
  const float* Wrel1 = (const float*)d_in[3];
  const float* brel1 = (const float*)d_in[4];
  const float* Wroot1= (const float*)d_in[5];
  const float* Wrel2 = (const float*)d_in[6];
  const float* brel2 = (const float*)d_in[7];
  const float* Wroot2= (const float*)d_in[8];
  const float* Wrel3 = (const float*)d_in[9];
  const float* brel3 = (const float*)d_in[10];
  const float* Wroot3= (const float*)d_in[11];
  const float* W1 = (const float*)d_in[12]; const float* b1 = (const float*)d_in[13];
  const float* W2 = (const float*)d_in[14]; const float* b2 = (const float*)d_in[15];
  const float* Wo = (const float*)d_in[16]; const float* bo = (const float*)d_in[17];
  const int* esrc = ei;
  const int* edst = ei + N_EDGES;

  char* ws = (char*)d_ws;
  size_t off = 0;
  auto alloc = [&](size_t bytes)->char*{
    char* p = ws + off; off += (bytes + 255) & ~(size_t)255; return p;
  };
  u16*   X1     = (u16*)  alloc((size_t)N_NODES*128*2);
  u16*   X2     = (u16*)  alloc((size_t)N_NODES*128*2);
  u16*   X3     = (u16*)  alloc((size_t)N_NODES*128*2);
  u16*   wcat   = (u16*)  alloc((size_t)2*128*256*2);
  u16*   wm     = (u16*)  alloc((size_t)2*128*128*2);
  u16*   Gb     = (u16*)  alloc((size_t)N_GRAPHS*128*2);
  u32*   rp     = (u32*)  alloc((size_t)N_NODES*4);
  int*   colIdx = (int*)  alloc((size_t)NBIN*MAXBIN*4);   // doubles as rec buffer
  int*   start  = (int*)  alloc((size_t)(N_GRAPHS+1)*4);
  int*   bincur = (int*)  alloc((size_t)NBIN*4);
  u32*   rec    = (u32*)colIdx;

  dim3 b256(256);
  hipMemsetAsync(bincur, 0, (size_t)NBIN*4, stream);
  k_prepsc <<<PREP_TOT, b256, 0, stream>>>((const float4*)x, (uint2*)X1,
                                           Wrel1, Wroot1, Wrel2, Wroot2, wcat,
                                           W1, W2, wm, batch, start,
                                           esrc, edst, bincur, rec);
  k_bincsr <<<NBIN, b256, 0, stream>>>(rec, bincur, rp, colIdx);

  k_layer  <<<NB64, b256, 0, stream>>>(X1, rp, colIdx, wcat + 0*32768, brel1, X2);
  k_layer  <<<NB64, b256, 0, stream>>>(X2, rp, colIdx, wcat + 1*32768, brel2, X3);

  k_aggpool<<<N_GRAPHS, dim3(512), 0, stream>>>(X3, rp, colIdx, start,
                                                Wrel3, Wroot3, brel3, Gb);
  k_mlp    <<<8, b256, 0, stream>>>(Gb, wm, b1, b2, Wo, bo, (float*)d_out);
}

// Round 2
// 284.376 us; speedup vs baseline: 1.0925x; 1.0925x over previous
//
#include <hip/hip_runtime.h>
#include <hip/hip_bf16.h>
#include <stdint.h>

#define N_NODES  50000
#define N_EDGES  800000
#define N_GRAPHS 512

#define BINSZ   128
#define NBIN    ((N_NODES + BINSZ - 1)/BINSZ)    // 391
#define NCHUNK  1024
#define CHUNK   ((N_EDGES + NCHUNK - 1)/NCHUNK)  // 782
#define MAXBIN  3072

typedef __attribute__((ext_vector_type(8))) short  short8;
typedef __attribute__((ext_vector_type(4))) float  floatx4;
typedef unsigned short u16;
typedef unsigned int   u32;

__device__ __forceinline__ u16 f2b(float f){
  u32 u = __float_as_uint(f);
  u = (u + 0x7FFFu + ((u >> 16) & 1u)) >> 16;   // RNE
  return (u16)u;
}
__device__ __forceinline__ u32 pack2(float a, float b){
  return (u32)f2b(a) | ((u32)f2b(b) << 16);
}
__device__ __forceinline__ float blo(u32 v){ return __uint_as_float(v << 16); }
__device__ __forceinline__ float bhi(u32 v){ return __uint_as_float(v & 0xFFFF0000u); }
__device__ __forceinline__ float b2f(u16 s){ return __uint_as_float(((u32)s) << 16); }

// gather-accumulate one node's neighbor rows (bf16 X, 128ch).
// half-waves (sub 0/1) process alternate edges; lane ln holds ch[4ln..4ln+3].
// 8-edge unroll keeps 4 independent row-loads in flight per half-wave.
__device__ __forceinline__ floatx4 gather_node(const uint2* __restrict__ Xu,
    const int* __restrict__ col, u32 r, int lane, int sub, int ln, int* degOut){
  int cs = (int)(r >> 11), d = (int)(r & 2047), ce = cs + d;
  float a0 = 0.f, a1 = 0.f, a2 = 0.f, a3 = 0.f;
  for (int cb = cs; cb < ce; cb += 64){
    int cnt = min(64, ce - cb);
    int idx = 0;
    if (cb + lane < ce) idx = col[cb + lane];
    int k = 0;
    for (; k + 8 <= cnt; k += 8){
      int jA = __shfl(idx, k + sub);
      int jB = __shfl(idx, k + 2 + sub);
      int jC = __shfl(idx, k + 4 + sub);
      int jD = __shfl(idx, k + 6 + sub);
      uint2 vA = Xu[jA*32 + ln];
      uint2 vB = Xu[jB*32 + ln];
      uint2 vC = Xu[jC*32 + ln];
      uint2 vD = Xu[jD*32 + ln];
      a0 += (blo(vA.x) + blo(vB.x)) + (blo(vC.x) + blo(vD.x));
      a1 += (bhi(vA.x) + bhi(vB.x)) + (bhi(vC.x) + bhi(vD.x));
      a2 += (blo(vA.y) + blo(vB.y)) + (blo(vC.y) + blo(vD.y));
      a3 += (bhi(vA.y) + bhi(vB.y)) + (bhi(vC.y) + bhi(vD.y));
    }
    for (; k + 2 <= cnt; k += 2){
      int j = __shfl(idx, k + sub);
      uint2 v = Xu[j*32 + ln];
      a0 += blo(v.x); a1 += bhi(v.x); a2 += blo(v.y); a3 += bhi(v.y);
    }
    if (k < cnt){
      int j = __shfl(idx, k);
      if (sub == 0){
        uint2 v = Xu[j*32 + ln];
        a0 += blo(v.x); a1 += bhi(v.x); a2 += blo(v.y); a3 += bhi(v.y);
      }
    }
  }
  a0 += __shfl_xor(a0, 32); a1 += __shfl_xor(a1, 32);
  a2 += __shfl_xor(a2, 32); a3 += __shfl_xor(a3, 32);
  *degOut = d;
  floatx4 out = {a0, a1, a2, a3};
  return out;
}

// ---- fused prep: SCATTER FIRST (latency-bound long pole), then cast/weights -
#define P_SC    NCHUNK
#define P_CAST  (P_SC + 6250)
#define P_W2    (P_CAST + 256)
#define P_MLP   (P_W2 + 128)
#define P_BND   (P_MLP + 3)
__launch_bounds__(256)
__global__ void k_prepsc(const float4* __restrict__ x, uint2* __restrict__ X1,
                         const float* __restrict__ Wrel1, const float* __restrict__ Wroot1,
                         const float* __restrict__ Wrel2, const float* __restrict__ Wroot2,
                         u16* __restrict__ wcat,
                         const float* __restrict__ W1, const float* __restrict__ W2,
                         u16* __restrict__ wm,
                         const int* __restrict__ batch, int* __restrict__ start,
                         const int* __restrict__ src, const int* __restrict__ dst,
                         int* __restrict__ bincur, u32* __restrict__ rec){
  __shared__ int h[NBIN];
  __shared__ int cur[NBIN];
  int blk = blockIdx.x, t = threadIdx.x;
  if (blk < P_SC){
    // scatter: fused hist + range-reserve (bincur is bin-LOCAL, zeroed by memset)
    for (int i = t; i < NBIN; i += 256) h[i] = 0;
    __syncthreads();
    int base = blk*CHUNK;
    int end  = min(base + CHUNK, N_EDGES);
    for (int i = base + t; i < end; i += 256) atomicAdd(&h[dst[i] >> 7], 1);
    __syncthreads();
    for (int i = t; i < NBIN; i += 256){
      int c = h[i];
      cur[i] = i*MAXBIN + (c ? atomicAdd(&bincur[i], c) : 0);
    }
    __syncthreads();
    for (int i = base + t; i < end; i += 256){
      int d = dst[i], sv = src[i];
      int b = d >> 7;
      int p = atomicAdd(&cur[b], 1);
      rec[p] = (u32)(((d & 127) << 16) | sv);
    }
  } else if (blk < P_CAST){
    int i = (blk - P_SC)*256 + t;              // exactly 1,600,000
    float4 v = x[i];
    X1[i] = make_uint2(pack2(v.x, v.y), pack2(v.z, v.w));
  } else if (blk < P_W2){
    int id = (blk - P_CAST)*256 + t;           // 65536
    int l = id >> 15;
    int r = id & 32767;
    int n = r >> 8;
    int k = r & 255;
    const float* Wrel  = l ? Wrel2  : Wrel1;
    const float* Wroot = l ? Wroot2 : Wroot1;
    float w = (k < 128) ? Wrel[k*128 + n] : Wroot[(k-128)*128 + n];
    int c = k >> 3, j = k & 7;
    wcat[l*32768 + n*256 + ((c ^ (n & 15)) << 3) + j] = f2b(w);
  } else if (blk < P_MLP){
    int id = (blk - P_W2)*256 + t;             // 32768
    int l = id >> 14;
    int r = id & 16383;
    int n = r >> 7;
    int k = r & 127;
    const float* W = l ? W2 : W1;
    wm[l*16384 + n*128 + k] = f2b(W[k*128 + n]);
  } else {
    int g = (blk - P_MLP)*256 + t;
    if (g <= N_GRAPHS){
      int lo = 0, hi = N_NODES;
      while (lo < hi){ int mid = (lo + hi) >> 1; if (batch[mid] < g) lo = mid + 1; else hi = mid; }
      start[g] = lo;
    }
  }
}

// ---- CSR step 2: per-bin node-ordered segment; rp[node] = (start<<11)|deg ---
__global__ void k_bincsr(const u32* __restrict__ rec, const int* __restrict__ bincur,
                         u32* __restrict__ rp, int* __restrict__ col){
  __shared__ u32 recs[MAXBIN];
  __shared__ int colL[MAXBIN];
  __shared__ int deg[BINSZ];
  __shared__ int cursor[BINSZ];
  __shared__ int sc[BINSZ];
  int b = blockIdx.x, t = threadIdx.x;
  int s0 = b*MAXBIN;
  int n = bincur[b];                 // bin-local count
  if (t < BINSZ) deg[t] = 0;
  for (int i = t; i < n; i += 256) recs[i] = rec[s0 + i];
  __syncthreads();
  for (int i = t; i < n; i += 256) atomicAdd(&deg[(recs[i] >> 16) & 127], 1);
  __syncthreads();
  if (t < BINSZ) sc[t] = deg[t];
  __syncthreads();
  for (int off = 1; off < BINSZ; off <<= 1){
    int u = 0;
    if (t < BINSZ && t >= off) u = sc[t - off];
    __syncthreads();
    if (t < BINSZ) sc[t] += u;
    __syncthreads();
  }
  if (t < BINSZ){
    int d = deg[t];
    int pref = sc[t] - d;
    cursor[t] = pref;
    int node = b*BINSZ + t;
    if (node < N_NODES) rp[node] = (u32)((s0 + pref) << 11) | (u32)min(d, 2047);
  }
  __syncthreads();
  for (int i = t; i < n; i += 256){
    u32 r = recs[i];
    int p = atomicAdd(&cursor[(r >> 16) & 127], 1);
    colL[p] = (int)(r & 0xFFFFu);
  }
  __syncthreads();
  for (int i = t; i < n; i += 256) col[s0 + i] = colL[i];
}

// ---- Aggregation: M[i] = (1/deg) * sum_{j in N(i)} X[j]  (bf16 out) --------
// One wave per node; 12500 blocks -> full TLP for the latency-bound gather.
__global__ void k_aggm(const u16* __restrict__ X, const u32* __restrict__ rp,
                       const int* __restrict__ col, u16* __restrict__ M){
  int wave = threadIdx.x >> 6, lane = threadIdx.x & 63;
  int node = blockIdx.x*4 + wave;                 // grid covers exactly 50000
  int sub = lane >> 5, ln = lane & 31;
  const uint2* Xu = (const uint2*)X;
  int d;
  floatx4 a = gather_node(Xu, col, rp[node], lane, sub, ln, &d);
  if (sub == 0){
    float di = 1.0f / (float)max(d, 1);
    ((uint2*)M)[node*32 + ln] = make_uint2(pack2(a[0]*di, a[1]*di), pack2(a[2]*di, a[3]*di));
  }
}

// ---- GEMM: Xout = relu([M|X] @ Wcat + brel)  (M=50000, K=256, N=128) ------
__launch_bounds__(256, 2)
__global__ void k_gemm2(const u16* __restrict__ M, const u16* __restrict__ X,
                        const u16* __restrict__ Wcat, const float* __restrict__ brel,
                        u16* __restrict__ Xout){
  __shared__ u16 Bs[128*256];
  {
    const uint4* s = (const uint4*)Wcat;
    uint4* d = (uint4*)Bs;
    #pragma unroll
    for (int i = 0; i < 16; i++) d[threadIdx.x + 256*i] = s[threadIdx.x + 256*i];
  }
  __syncthreads();

  int wave = threadIdx.x >> 6, lane = threadIdx.x & 63;
  int l15 = lane & 15, quad = lane >> 4;
  int wy = wave >> 1, wx = wave & 1;
  int rowBase = blockIdx.x*128 + wy*64;

  floatx4 acc[4][4] = {};

  #pragma unroll
  for (int k0 = 0; k0 < 256; k0 += 32){
    const u16* Asrc = (k0 < 128) ? M : X;
    int kk = k0 & 127;
    int c = (k0 >> 3) + quad;
    short8 a[4];
    #pragma unroll
    for (int mt = 0; mt < 4; mt++){
      int row = rowBase + mt*16 + l15;
      if (row > N_NODES-1) row = N_NODES-1;   // clamp; stores are masked
      a[mt] = *(const short8*)(Asrc + row*128 + kk + quad*8);
    }
    #pragma unroll
    for (int nt = 0; nt < 4; nt++){
      int n = wx*64 + nt*16 + l15;
      short8 b = *(const short8*)(Bs + n*256 + ((c ^ (n & 15)) << 3));
      #pragma unroll
      for (int mt = 0; mt < 4; mt++)
        acc[mt][nt] = __builtin_amdgcn_mfma_f32_16x16x32_bf16(a[mt], b, acc[mt][nt], 0, 0, 0);
    }
  }

  float bc[4];
  #pragma unroll
  for (int nt = 0; nt < 4; nt++) bc[nt] = brel[wx*64 + nt*16 + l15];

  #pragma unroll
  for (int mt = 0; mt < 4; mt++){
    int rbase = rowBase + mt*16 + quad*4;
    #pragma unroll
    for (int r = 0; r < 4; r++){
      int row = rbase + r;
      if (row < N_NODES){
        #pragma unroll
        for (int nt = 0; nt < 4; nt++){
          int n = wx*64 + nt*16 + l15;
          Xout[row*128 + n] = f2b(fmaxf(acc[mt][nt][r] + bc[nt], 0.f));
        }
      }
    }
  }
}

// ---- fused agg3 + pool + conv3: Gb[g] = pool(agg(X3))@Wrel3 + pool(X3)@Wroot3 + brel3
// pooled-mean of per-node means is linear: no per-node M3 is materialized.
// 1024 threads x 512 blocks = exactly 2 blocks/CU -> 100% occupancy gather.
__launch_bounds__(1024)
__global__ void k_aggpool(const u16* __restrict__ X3, const u32* __restrict__ rp,
                          const int* __restrict__ col, const int* __restrict__ start,
                          const float* __restrict__ Wrel, const float* __restrict__ Wroot,
                          const float* __restrict__ brel, u16* __restrict__ Gb){
  __shared__ float smM[16][128];
  __shared__ float smX[16][128];
  __shared__ float pmS[128], pxS[128], part[256];
  int g = blockIdx.x;
  int t = threadIdx.x, wave = t >> 6, lane = t & 63;
  int sub = lane >> 5, ln = lane & 31;
  int s = start[g], e = start[g+1];
  const uint2* Xu = (const uint2*)X3;

  float gm0=0.f, gm1=0.f, gm2=0.f, gm3=0.f;
  for (int i = s + wave; i < e; i += 16){
    int d;
    floatx4 a = gather_node(Xu, col, rp[i], lane, sub, ln, &d);
    float di = 1.0f / (float)max(d, 1);
    gm0 += a[0]*di; gm1 += a[1]*di; gm2 += a[2]*di; gm3 += a[3]*di;
  }
  float gx0=0.f, gx1=0.f, gx2=0.f, gx3=0.f;
  for (int i = s + wave*2 + sub; i < e; i += 32){
    uint2 v = Xu[i*32 + ln];
    gx0 += blo(v.x); gx1 += bhi(v.x); gx2 += blo(v.y); gx3 += bhi(v.y);
  }
  gx0 += __shfl_xor(gx0, 32); gx1 += __shfl_xor(gx1, 32);
  gx2 += __shfl_xor(gx2, 32); gx3 += __shfl_xor(gx3, 32);
  if (sub == 0){
    smM[wave][4*ln+0] = gm0; smM[wave][4*ln+1] = gm1;
    smM[wave][4*ln+2] = gm2; smM[wave][4*ln+3] = gm3;
    smX[wave][4*ln+0] = gx0; smX[wave][4*ln+1] = gx1;
    smX[wave][4*ln+2] = gx2; smX[wave][4*ln+3] = gx3;
  }
  __syncthreads();
  if (t < 128){
    float inv = 1.0f / (float)max(e - s, 1);
    float m = 0.f, xx = 0.f;
    #pragma unroll
    for (int w = 0; w < 16; w++){ m += smM[w][t]; xx += smX[w][t]; }
    pmS[t] = m*inv; pxS[t] = xx*inv;
  }
  __syncthreads();
  if (t < 256){
    int n = t & 127, half = t >> 7;
    const float* W = half ? Wroot : Wrel;
    const float* S = half ? pxS : pmS;
    float a = 0.f;
    for (int k = 0; k < 128; k++) a = fmaf(S[k], W[k*128 + n], a);
    part[t] = a;
  }
  __syncthreads();
  if (t < 128) Gb[g*128 + t] = f2b(part[t] + part[t + 128] + brel[t]);
}

// ---- fused MLP (8 blocks x 64 rows) ----------------------------------------
#define APAD 136
__launch_bounds__(256)
__global__ void k_mlp(const u16* __restrict__ Gb, const u16* __restrict__ wm,
                      const float* __restrict__ b1, const float* __restrict__ b2,
                      const float* __restrict__ Wo, const float* __restrict__ bo,
                      float* __restrict__ out){
  __shared__ u16 Apad[64*APAD];
  int t = threadIdx.x;
  int wave = t >> 6, lane = t & 63;
  int l15 = lane & 15, quad = lane >> 4;
  int R = blockIdx.x*64;

  floatx4 acc[8] = {};
  #pragma unroll
  for (int k0 = 0; k0 < 128; k0 += 32){
    int row = R + wave*16 + l15;
    short8 a = *(const short8*)(Gb + row*128 + k0 + quad*8);
    #pragma unroll
    for (int nt = 0; nt < 8; nt++){
      short8 b = *(const short8*)(wm + (nt*16 + l15)*128 + k0 + quad*8);
      acc[nt] = __builtin_amdgcn_mfma_f32_16x16x32_bf16(a, b, acc[nt], 0, 0, 0);
    }
  }
  #pragma unroll
  for (int nt = 0; nt < 8; nt++){
    int coln = nt*16 + l15;
    float bc = b1[coln];
    int lmb = wave*16 + quad*4;
    #pragma unroll
    for (int r = 0; r < 4; r++)
      Apad[(lmb + r)*APAD + coln] = f2b(fmaxf(acc[nt][r] + bc, 0.f));
  }
  __syncthreads();

  floatx4 acc2[8] = {};
  #pragma unroll
  for (int k0 = 0; k0 < 128; k0 += 32){
    short8 a = *(const short8*)(Apad + (wave*16 + l15)*APAD + k0 + quad*8);
    #pragma unroll
    for (int nt = 0; nt < 8; nt++){
      short8 b = *(const short8*)(wm + 16384 + (nt*16 + l15)*128 + k0 + quad*8);
      acc2[nt] = __builtin_amdgcn_mfma_f32_16x16x32_bf16(a, b, acc2[nt], 0, 0, 0);
    }
  }
  __syncthreads();
  #pragma unroll
  for (int nt = 0; nt < 8; nt++){
    int coln = nt*16 + l15;
    float bc = b2[coln];
    int lmb = wave*16 + quad*4;
    #pragma unroll
    for (int r = 0; r < 4; r++)
      Apad[(lmb + r)*APAD + coln] = f2b(fmaxf(acc2[nt][r] + bc, 0.f));
  }
  __syncthreads();

  if (t < 128){
    int row = t >> 1;
    int c0  = (t & 1)*4;
    float o0 = bo[c0], o1 = bo[c0+1], o2 = bo[c0+2], o3 = bo[c0+3];
    for (int k = 0; k < 128; k++){
      float h = b2f(Apad[row*APAD + k]);
      const float* w = Wo + k*8 + c0;
      o0 = fmaf(h, w[0], o0); o1 = fmaf(h, w[1], o1);
      o2 = fmaf(h, w[2], o2); o3 = fmaf(h, w[3], o3);
    }
    float* op = out + (R + row)*8 + c0;
    op[0] = o0; op[1] = o1; op[2] = o2; op[3] = o3;
  }
}

extern "C" void kernel_launch(void* const* d_in, const int* in_sizes, int n_in,
                              void* d_out, int out_size, void* d_ws, size_t ws_size,
                              hipStream_t stream){
  const float* x     = (const float*)d_in[0];
  const int*   ei    = (const int*)d_in[1];
  const int*   batch = (const int*)d_in[2];
  const float* Wrel1 = (const float*)d_in[3];
  const float* brel1 = (const float*)d_in[4];
  const float* Wroot1= (const float*)d_in[5];
  const float* Wrel2 = (const float*)d_in[6];
  const float* brel2 = (const float*)d_in[7];
  const float* Wroot2= (const float*)d_in[8];
  const float* Wrel3 = (const float*)d_in[9];
  const float* brel3 = (const float*)d_in[10];
  const float* Wroot3= (const float*)d_in[11];
  const float* W1 = (const float*)d_in[12]; const float* b1 = (const float*)d_in[13];
  const float* W2 = (const float*)d_in[14]; const float* b2 = (const float*)d_in[15];
  const float* Wo = (const float*)d_in[16]; const float* bo = (const float*)d_in[17];
  const int* esrc = ei;
  const int* edst = ei + N_EDGES;

  char* ws = (char*)d_ws;
  size_t off = 0;
  auto alloc = [&](size_t bytes)->char*{
    char* p = ws + off; off += (bytes + 255) & ~(size_t)255; return p;
  };
  u16*   X1     = (u16*)  alloc((size_t)N_NODES*128*2);
  u16*   X2     = (u16*)  alloc((size_t)N_NODES*128*2);
  u16*   X3     = (u16*)  alloc((size_t)N_NODES*128*2);
  u16*   Mb     = (u16*)  alloc((size_t)N_NODES*128*2);
  u16*   wcat   = (u16*)  alloc((size_t)2*128*256*2);
  u16*   wm     = (u16*)  alloc((size_t)2*128*128*2);
  u16*   Gb     = (u16*)  alloc((size_t)N_GRAPHS*128*2);
  u32*   rp     = (u32*)  alloc((size_t)N_NODES*4);
  int*   colIdx = (int*)  alloc((size_t)NBIN*MAXBIN*4);   // doubles as rec buffer
  int*   start  = (int*)  alloc((size_t)(N_GRAPHS+1)*4);
  int*   bincur = (int*)  alloc((size_t)NBIN*4);
  u32*   rec    = (u32*)colIdx;

  dim3 b256(256);
  hipMemsetAsync(bincur, 0, (size_t)NBIN*4, stream);
  k_prepsc <<<P_BND, b256, 0, stream>>>((const float4*)x, (uint2*)X1,
                                        Wrel1, Wroot1, Wrel2, Wroot2, wcat,
                                        W1, W2, wm, batch, start,
                                        esrc, edst, bincur, rec);
  k_bincsr <<<NBIN, b256, 0, stream>>>(rec, bincur, rp, colIdx);

  const int ggrid = (N_NODES + 127)/128;   // 391
  const int agrid = N_NODES/4;             // 12500

  k_aggm <<<agrid, b256, 0, stream>>>(X1, rp, colIdx, Mb);
  k_gemm2<<<ggrid, b256, 0, stream>>>(Mb, X1, wcat + 0*32768, brel1, X2);

  k_aggm <<<agrid, b256, 0, stream>>>(X2, rp, colIdx, Mb);
  k_gemm2<<<ggrid, b256, 0, stream>>>(Mb, X2, wcat + 1*32768, brel2, X3);

  k_aggpool<<<N_GRAPHS, dim3(1024), 0, stream>>>(X3, rp, colIdx, start,
                                                 Wrel3, Wroot3, brel3, Gb);
  k_mlp    <<<8, b256, 0, stream>>>(Gb, wm, b1, b2, Wo, bo, (float*)d_out);
}

// Round 3
// 258.463 us; speedup vs baseline: 1.2021x; 1.1003x over previous
//
#include <hip/hip_runtime.h>
#include <hip/hip_bf16.h>
#include <stdint.h>

#define N_NODES  50000
#define N_EDGES  800000
#define N_GRAPHS 512

#define BINSZ   128
#define NBIN    ((N_NODES + BINSZ - 1)/BINSZ)    // 391
#define MAXBIN  3072
#define NSCAT   256
#define SCHUNK  ((N_EDGES + NSCAT - 1)/NSCAT)    // 3125

typedef __attribute__((ext_vector_type(8))) short  short8;
typedef __attribute__((ext_vector_type(4))) float  floatx4;
typedef unsigned short u16;
typedef unsigned int   u32;

__device__ __forceinline__ u16 f2b(float f){
  u32 u = __float_as_uint(f);
  u = (u + 0x7FFFu + ((u >> 16) & 1u)) >> 16;   // RNE
  return (u16)u;
}
__device__ __forceinline__ u32 pack2(float a, float b){
  return (u32)f2b(a) | ((u32)f2b(b) << 16);
}
__device__ __forceinline__ float blo(u32 v){ return __uint_as_float(v << 16); }
__device__ __forceinline__ float bhi(u32 v){ return __uint_as_float(v & 0xFFFF0000u); }
__device__ __forceinline__ float b2f(u16 s){ return __uint_as_float(((u32)s) << 16); }

// gather-accumulate one node's neighbor rows (bf16 X, 128ch).
// half-waves (sub 0/1) process alternate edges; lane ln holds ch[4ln..4ln+3].
// 8-edge unroll keeps 4 independent row-loads in flight per half-wave.
__device__ __forceinline__ floatx4 gather_node(const uint2* __restrict__ Xu,
    const int* __restrict__ col, u32 r, int lane, int sub, int ln, int* degOut){
  int cs = (int)(r >> 11), d = (int)(r & 2047), ce = cs + d;
  float a0 = 0.f, a1 = 0.f, a2 = 0.f, a3 = 0.f;
  for (int cb = cs; cb < ce; cb += 64){
    int cnt = min(64, ce - cb);
    int idx = 0;
    if (cb + lane < ce) idx = col[cb + lane];
    int k = 0;
    for (; k + 8 <= cnt; k += 8){
      int jA = __shfl(idx, k + sub);
      int jB = __shfl(idx, k + 2 + sub);
      int jC = __shfl(idx, k + 4 + sub);
      int jD = __shfl(idx, k + 6 + sub);
      uint2 vA = Xu[jA*32 + ln];
      uint2 vB = Xu[jB*32 + ln];
      uint2 vC = Xu[jC*32 + ln];
      uint2 vD = Xu[jD*32 + ln];
      a0 += (blo(vA.x) + blo(vB.x)) + (blo(vC.x) + blo(vD.x));
      a1 += (bhi(vA.x) + bhi(vB.x)) + (bhi(vC.x) + bhi(vD.x));
      a2 += (blo(vA.y) + blo(vB.y)) + (blo(vC.y) + blo(vD.y));
      a3 += (bhi(vA.y) + bhi(vB.y)) + (bhi(vC.y) + bhi(vD.y));
    }
    for (; k + 2 <= cnt; k += 2){
      int j = __shfl(idx, k + sub);
      uint2 v = Xu[j*32 + ln];
      a0 += blo(v.x); a1 += bhi(v.x); a2 += blo(v.y); a3 += bhi(v.y);
    }
    if (k < cnt){
      int j = __shfl(idx, k);
      if (sub == 0){
        uint2 v = Xu[j*32 + ln];
        a0 += blo(v.x); a1 += bhi(v.x); a2 += blo(v.y); a3 += bhi(v.y);
      }
    }
  }
  a0 += __shfl_xor(a0, 32); a1 += __shfl_xor(a1, 32);
  a2 += __shfl_xor(a2, 32); a3 += __shfl_xor(a3, 32);
  *degOut = d;
  floatx4 out = {a0, a1, a2, a3};
  return out;
}

// ---- coalesced scatter: register-staged, locally bin-sorted ----------------
// rec packs dst<<16 | src (both < 65536). Writes are position-ordered ->
// runs of ~8 consecutive records per bin -> coalesced bursts.
__launch_bounds__(1024)
__global__ void k_scatter(const int* __restrict__ src, const int* __restrict__ dst,
                          int* __restrict__ bincur, u32* __restrict__ rec){
  __shared__ int h[NBIN];
  __shared__ int gadj[NBIN];
  __shared__ int cursor[NBIN];
  __shared__ int wsum[8];
  __shared__ u32 st[SCHUNK];
  int t = threadIdx.x;
  int base = blockIdx.x*SCHUNK;
  int end  = min(base + SCHUNK, N_EDGES);
  int cnt  = end - base;
  for (int i = t; i < NBIN; i += 1024) h[i] = 0;
  __syncthreads();
  u32 r[4]; int nb[4]; int ne = 0;
  for (int i = base + t; i < end; i += 1024){
    int d = dst[i], s = src[i];
    r[ne]  = ((u32)d << 16) | (u32)s;
    nb[ne] = d >> 7;
    atomicAdd(&h[nb[ne]], 1);
    ne++;
  }
  __syncthreads();
  // block-level exclusive scan over 391 bins (shfl within 64-lane waves)
  int hv = 0, incl = 0;
  if (t < NBIN){
    hv = h[t];
    incl = hv;
    int lane = t & 63;
    #pragma unroll
    for (int off = 1; off < 64; off <<= 1){
      int n = __shfl_up(incl, off);
      if (lane >= off) incl += n;
    }
    if (lane == 63 || t == NBIN-1) wsum[t >> 6] = incl;
  }
  __syncthreads();
  if (t < NBIN){
    int g = t >> 6;
    int pre = 0;
    for (int gg = 0; gg < g; gg++) pre += wsum[gg];
    int o = pre + incl - hv;                 // exclusive offset of bin t
    cursor[t] = o;
    int gb = t*MAXBIN + (hv ? atomicAdd(&bincur[t], hv) : 0);
    gadj[t] = gb - o;
  }
  __syncthreads();
  for (int j = 0; j < ne; j++){
    int p = atomicAdd(&cursor[nb[j]], 1);
    st[p] = r[j];
  }
  __syncthreads();
  for (int i = t; i < cnt; i += 1024){
    u32 v = st[i];
    rec[gadj[v >> 23] + i] = v;              // v>>23 == dst>>7 == bin
  }
}

// ---- CSR step 2 (391 blocks) fused with cast/weight-prep/bounds ------------
#define C_BIN   NBIN
#define C_CAST  (C_BIN + 6250)
#define C_W2    (C_CAST + 256)
#define C_MLP   (C_W2 + 128)
#define C_BND   (C_MLP + 3)
__launch_bounds__(256)
__global__ void k_csrprep(const u32* __restrict__ rec, const int* __restrict__ bincur,
                          u32* __restrict__ rp, int* __restrict__ col,
                          const float4* __restrict__ x, uint2* __restrict__ X1,
                          const float* __restrict__ Wrel1, const float* __restrict__ Wroot1,
                          const float* __restrict__ Wrel2, const float* __restrict__ Wroot2,
                          u16* __restrict__ wcat,
                          const float* __restrict__ W1, const float* __restrict__ W2,
                          u16* __restrict__ wm,
                          const int* __restrict__ batch, int* __restrict__ start){
  __shared__ u32 recs[MAXBIN];
  __shared__ int colL[MAXBIN];
  __shared__ int deg[BINSZ];
  __shared__ int cursor[BINSZ];
  __shared__ int sc[BINSZ];
  int blk = blockIdx.x, t = threadIdx.x;
  if (blk < C_BIN){
    int b = blk;
    int s0 = b*MAXBIN;
    int n = bincur[b];                 // bin-local count
    if (t < BINSZ) deg[t] = 0;
    for (int i = t; i < n; i += 256) recs[i] = rec[s0 + i];
    __syncthreads();
    for (int i = t; i < n; i += 256) atomicAdd(&deg[(recs[i] >> 16) & 127], 1);
    __syncthreads();
    if (t < BINSZ) sc[t] = deg[t];
    __syncthreads();
    for (int off = 1; off < BINSZ; off <<= 1){
      int u = 0;
      if (t < BINSZ && t >= off) u = sc[t - off];
      __syncthreads();
      if (t < BINSZ) sc[t] += u;
      __syncthreads();
    }
    if (t < BINSZ){
      int d = deg[t];
      int pref = sc[t] - d;
      cursor[t] = pref;
      int node = b*BINSZ + t;
      if (node < N_NODES) rp[node] = (u32)((s0 + pref) << 11) | (u32)min(d, 2047);
    }
    __syncthreads();
    for (int i = t; i < n; i += 256){
      u32 r = recs[i];
      int p = atomicAdd(&cursor[(r >> 16) & 127], 1);
      colL[p] = (int)(r & 0xFFFFu);
    }
    __syncthreads();
    for (int i = t; i < n; i += 256) col[s0 + i] = colL[i];
  } else if (blk < C_CAST){
    int i = (blk - C_BIN)*256 + t;             // exactly 1,600,000
    float4 v = x[i];
    X1[i] = make_uint2(pack2(v.x, v.y), pack2(v.z, v.w));
  } else if (blk < C_W2){
    int id = (blk - C_CAST)*256 + t;           // 65536
    int l = id >> 15;
    int r = id & 32767;
    int n = r >> 8;
    int k = r & 255;
    const float* Wrel  = l ? Wrel2  : Wrel1;
    const float* Wroot = l ? Wroot2 : Wroot1;
    float w = (k < 128) ? Wrel[k*128 + n] : Wroot[(k-128)*128 + n];
    int c = k >> 3, j = k & 7;
    wcat[l*32768 + n*256 + ((c ^ (n & 15)) << 3) + j] = f2b(w);
  } else if (blk < C_MLP){
    int id = (blk - C_W2)*256 + t;             // 32768
    int l = id >> 14;
    int r = id & 16383;
    int n = r >> 7;
    int k = r & 127;
    const float* W = l ? W2 : W1;
    wm[l*16384 + n*128 + k] = f2b(W[k*128 + n]);
  } else {
    int g = (blk - C_MLP)*256 + t;
    if (g <= N_GRAPHS){
      int lo = 0, hi = N_NODES;
      while (lo < hi){ int mid = (lo + hi) >> 1; if (batch[mid] < g) lo = mid + 1; else hi = mid; }
      start[g] = lo;
    }
  }
}

// ---- Aggregation: M[i] = (1/deg) * sum_{j in N(i)} X[j]  (bf16 out) --------
__global__ void k_aggm(const u16* __restrict__ X, const u32* __restrict__ rp,
                       const int* __restrict__ col, u16* __restrict__ M){
  int wave = threadIdx.x >> 6, lane = threadIdx.x & 63;
  int node = blockIdx.x*4 + wave;                 // grid covers exactly 50000
  int sub = lane >> 5, ln = lane & 31;
  const uint2* Xu = (const uint2*)X;
  int d;
  floatx4 a = gather_node(Xu, col, rp[node], lane, sub, ln, &d);
  if (sub == 0){
    float di = 1.0f / (float)max(d, 1);
    ((uint2*)M)[node*32 + ln] = make_uint2(pack2(a[0]*di, a[1]*di), pack2(a[2]*di, a[3]*di));
  }
}

// ---- GEMM: Xout = relu([M|X] @ Wcat + brel)  (M=50000, K=256, N=128) ------
__launch_bounds__(256, 2)
__global__ void k_gemm2(const u16* __restrict__ M, const u16* __restrict__ X,
                        const u16* __restrict__ Wcat, const float* __restrict__ brel,
                        u16* __restrict__ Xout){
  __shared__ u16 Bs[128*256];
  {
    const uint4* s = (const uint4*)Wcat;
    uint4* d = (uint4*)Bs;
    #pragma unroll
    for (int i = 0; i < 16; i++) d[threadIdx.x + 256*i] = s[threadIdx.x + 256*i];
  }
  __syncthreads();

  int wave = threadIdx.x >> 6, lane = threadIdx.x & 63;
  int l15 = lane & 15, quad = lane >> 4;
  int wy = wave >> 1, wx = wave & 1;
  int rowBase = blockIdx.x*128 + wy*64;

  floatx4 acc[4][4] = {};

  #pragma unroll
  for (int k0 = 0; k0 < 256; k0 += 32){
    const u16* Asrc = (k0 < 128) ? M : X;
    int kk = k0 & 127;
    int c = (k0 >> 3) + quad;
    short8 a[4];
    #pragma unroll
    for (int mt = 0; mt < 4; mt++){
      int row = rowBase + mt*16 + l15;
      if (row > N_NODES-1) row = N_NODES-1;   // clamp; stores are masked
      a[mt] = *(const short8*)(Asrc + row*128 + kk + quad*8);
    }
    #pragma unroll
    for (int nt = 0; nt < 4; nt++){
      int n = wx*64 + nt*16 + l15;
      short8 b = *(const short8*)(Bs + n*256 + ((c ^ (n & 15)) << 3));
      #pragma unroll
      for (int mt = 0; mt < 4; mt++)
        acc[mt][nt] = __builtin_amdgcn_mfma_f32_16x16x32_bf16(a[mt], b, acc[mt][nt], 0, 0, 0);
    }
  }

  float bc[4];
  #pragma unroll
  for (int nt = 0; nt < 4; nt++) bc[nt] = brel[wx*64 + nt*16 + l15];

  #pragma unroll
  for (int mt = 0; mt < 4; mt++){
    int rbase = rowBase + mt*16 + quad*4;
    #pragma unroll
    for (int r = 0; r < 4; r++){
      int row = rbase + r;
      if (row < N_NODES){
        #pragma unroll
        for (int nt = 0; nt < 4; nt++){
          int n = wx*64 + nt*16 + l15;
          Xout[row*128 + n] = f2b(fmaxf(acc[mt][nt][r] + bc[nt], 0.f));
        }
      }
    }
  }
}

// ---- fused agg3 + pool + conv3 ---------------------------------------------
__launch_bounds__(1024)
__global__ void k_aggpool(const u16* __restrict__ X3, const u32* __restrict__ rp,
                          const int* __restrict__ col, const int* __restrict__ start,
                          const float* __restrict__ Wrel, const float* __restrict__ Wroot,
                          const float* __restrict__ brel, u16* __restrict__ Gb){
  __shared__ float smM[16][128];
  __shared__ float smX[16][128];
  __shared__ float pmS[128], pxS[128], part[256];
  int g = blockIdx.x;
  int t = threadIdx.x, wave = t >> 6, lane = t & 63;
  int sub = lane >> 5, ln = lane & 31;
  int s = start[g], e = start[g+1];
  const uint2* Xu = (const uint2*)X3;

  float gm0=0.f, gm1=0.f, gm2=0.f, gm3=0.f;
  for (int i = s + wave; i < e; i += 16){
    int d;
    floatx4 a = gather_node(Xu, col, rp[i], lane, sub, ln, &d);
    float di = 1.0f / (float)max(d, 1);
    gm0 += a[0]*di; gm1 += a[1]*di; gm2 += a[2]*di; gm3 += a[3]*di;
  }
  float gx0=0.f, gx1=0.f, gx2=0.f, gx3=0.f;
  for (int i = s + wave*2 + sub; i < e; i += 32){
    uint2 v = Xu[i*32 + ln];
    gx0 += blo(v.x); gx1 += bhi(v.x); gx2 += blo(v.y); gx3 += bhi(v.y);
  }
  gx0 += __shfl_xor(gx0, 32); gx1 += __shfl_xor(gx1, 32);
  gx2 += __shfl_xor(gx2, 32); gx3 += __shfl_xor(gx3, 32);
  if (sub == 0){
    smM[wave][4*ln+0] = gm0; smM[wave][4*ln+1] = gm1;
    smM[wave][4*ln+2] = gm2; smM[wave][4*ln+3] = gm3;
    smX[wave][4*ln+0] = gx0; smX[wave][4*ln+1] = gx1;
    smX[wave][4*ln+2] = gx2; smX[wave][4*ln+3] = gx3;
  }
  __syncthreads();
  if (t < 128){
    float inv = 1.0f / (float)max(e - s, 1);
    float m = 0.f, xx = 0.f;
    #pragma unroll
    for (int w = 0; w < 16; w++){ m += smM[w][t]; xx += smX[w][t]; }
    pmS[t] = m*inv; pxS[t] = xx*inv;
  }
  __syncthreads();
  if (t < 256){
    int n = t & 127, half = t >> 7;
    const float* W = half ? Wroot : Wrel;
    const float* S = half ? pxS : pmS;
    float a = 0.f;
    for (int k = 0; k < 128; k++) a = fmaf(S[k], W[k*128 + n], a);
    part[t] = a;
  }
  __syncthreads();
  if (t < 128) Gb[g*128 + t] = f2b(part[t] + part[t + 128] + brel[t]);
}

// ---- fused MLP (8 blocks x 64 rows) ----------------------------------------
#define APAD 136
__launch_bounds__(256)
__global__ void k_mlp(const u16* __restrict__ Gb, const u16* __restrict__ wm,
                      const float* __restrict__ b1, const float* __restrict__ b2,
                      const float* __restrict__ Wo, const float* __restrict__ bo,
                      float* __restrict__ out){
  __shared__ u16 Apad[64*APAD];
  int t = threadIdx.x;
  int wave = t >> 6, lane = t & 63;
  int l15 = lane & 15, quad = lane >> 4;
  int R = blockIdx.x*64;

  floatx4 acc[8] = {};
  #pragma unroll
  for (int k0 = 0; k0 < 128; k0 += 32){
    int row = R + wave*16 + l15;
    short8 a = *(const short8*)(Gb + row*128 + k0 + quad*8);
    #pragma unroll
    for (int nt = 0; nt < 8; nt++){
      short8 b = *(const short8*)(wm + (nt*16 + l15)*128 + k0 + quad*8);
      acc[nt] = __builtin_amdgcn_mfma_f32_16x16x32_bf16(a, b, acc[nt], 0, 0, 0);
    }
  }
  #pragma unroll
  for (int nt = 0; nt < 8; nt++){
    int coln = nt*16 + l15;
    float bc = b1[coln];
    int lmb = wave*16 + quad*4;
    #pragma unroll
    for (int r = 0; r < 4; r++)
      Apad[(lmb + r)*APAD + coln] = f2b(fmaxf(acc[nt][r] + bc, 0.f));
  }
  __syncthreads();

  floatx4 acc2[8] = {};
  #pragma unroll
  for (int k0 = 0; k0 < 128; k0 += 32){
    short8 a = *(const short8*)(Apad + (wave*16 + l15)*APAD + k0 + quad*8);
    #pragma unroll
    for (int nt = 0; nt < 8; nt++){
      short8 b = *(const short8*)(wm + 16384 + (nt*16 + l15)*128 + k0 + quad*8);
      acc2[nt] = __builtin_amdgcn_mfma_f32_16x16x32_bf16(a, b, acc2[nt], 0, 0, 0);
    }
  }
  __syncthreads();
  #pragma unroll
  for (int nt = 0; nt < 8; nt++){
    int coln = nt*16 + l15;
    float bc = b2[coln];
    int lmb = wave*16 + quad*4;
    #pragma unroll
    for (int r = 0; r < 4; r++)
      Apad[(lmb + r)*APAD + coln] = f2b(fmaxf(acc2[nt][r] + bc, 0.f));
  }
  __syncthreads();

  if (t < 128){
    int row = t >> 1;
    int c0  = (t & 1)*4;
    float o0 = bo[c0], o1 = bo[c0+1], o2 = bo[c0+2], o3 = bo[c0+3];
    for (int k = 0; k < 128; k++){
      float h = b2f(Apad[row*APAD + k]);
      const float* w = Wo + k*8 + c0;
      o0 = fmaf(h, w[0], o0); o1 = fmaf(h, w[1], o1);
      o2 = fmaf(h, w[2], o2); o3 = fmaf(h, w[3], o3);
    }
    float* op = out + (R + row)*8 + c0;
    op[0] = o0; op[1] = o1; op[2] = o2; op[3] = o3;
  }
}

extern "C" void kernel_launch(void* const* d_in, const int* in_sizes, int n_in,
                              void* d_out, int out_size, void* d_ws, size_t ws_size,
                              hipStream_t stream){
  const float* x     = (const float*)d_in[0];
  const int*   ei    = (const int*)d_in[1];
  const int*   batch = (const int*)d_in[2];
  const float* Wrel1 = (const float*)d_in[3];
  const float* brel1 = (const float*)d_in[4];
  const float* Wroot1= (const float*)d_in[5];
  const float* Wrel2 = (const float*)d_in[6];
  const float* brel2 = (const float*)d_in[7];
  const float* Wroot2= (const float*)d_in[8];
  const float* Wrel3 = (const float*)d_in[9];
  const float* brel3 = (const float*)d_in[10];
  const float* Wroot3= (const float*)d_in[11];
  const float* W1 = (const float*)d_in[12]; const float* b1 = (const float*)d_in[13];
  const float* W2 = (const float*)d_in[14]; const float* b2 = (const float*)d_in[15];
  const float* Wo = (const float*)d_in[16]; const float* bo = (const float*)d_in[17];
  const int* esrc = ei;
  const int* edst = ei + N_EDGES;

  char* ws = (char*)d_ws;
  size_t off = 0;
  auto alloc = [&](size_t bytes)->char*{
    char* p = ws + off; off += (bytes + 255) & ~(size_t)255; return p;
  };
  u16*   X1     = (u16*)  alloc((size_t)N_NODES*128*2);
  u16*   X2     = (u16*)  alloc((size_t)N_NODES*128*2);
  u16*   X3     = (u16*)  alloc((size_t)N_NODES*128*2);
  u16*   Mb     = (u16*)  alloc((size_t)N_NODES*128*2);
  u16*   wcat   = (u16*)  alloc((size_t)2*128*256*2);
  u16*   wm     = (u16*)  alloc((size_t)2*128*128*2);
  u16*   Gb     = (u16*)  alloc((size_t)N_GRAPHS*128*2);
  u32*   rp     = (u32*)  alloc((size_t)N_NODES*4);
  int*   colIdx = (int*)  alloc((size_t)NBIN*MAXBIN*4);   // doubles as rec buffer
  int*   start  = (int*)  alloc((size_t)(N_GRAPHS+1)*4);
  int*   bincur = (int*)  alloc((size_t)NBIN*4);
  u32*   rec    = (u32*)colIdx;

  dim3 b256(256);
  hipMemsetAsync(bincur, 0, (size_t)NBIN*4, stream);
  k_scatter<<<NSCAT, dim3(1024), 0, stream>>>(esrc, edst, bincur, rec);
  k_csrprep<<<C_BND, b256, 0, stream>>>(rec, bincur, rp, colIdx,
                                        (const float4*)x, (uint2*)X1,
                                        Wrel1, Wroot1, Wrel2, Wroot2, wcat,
                                        W1, W2, wm, batch, start);

  const int ggrid = (N_NODES + 127)/128;   // 391
  const int agrid = N_NODES/4;             // 12500

  k_aggm <<<agrid, b256, 0, stream>>>(X1, rp, colIdx, Mb);
  k_gemm2<<<ggrid, b256, 0, stream>>>(Mb, X1, wcat + 0*32768, brel1, X2);

  k_aggm <<<agrid, b256, 0, stream>>>(X2, rp, colIdx, Mb);
  k_gemm2<<<ggrid, b256, 0, stream>>>(Mb, X2, wcat + 1*32768, brel2, X3);

  k_aggpool<<<N_GRAPHS, dim3(1024), 0, stream>>>(X3, rp, colIdx, start,
                                                 Wrel3, Wroot3, brel3, Gb);
  k_mlp    <<<8, b256, 0, stream>>>(Gb, wm, b1, b2, Wo, bo, (float*)d_out);
}